// Round 1
// baseline (384.357 us; speedup 1.0000x reference)
//
#include <hip/hip_runtime.h>
#include <hip/hip_bf16.h>

typedef __attribute__((ext_vector_type(8))) short s16x8;
typedef __attribute__((ext_vector_type(4))) float f32x4;

#define BATCH 8
#define NPIX  4096
#define CCH   256
#define RCH   32

__device__ __forceinline__ unsigned short f2bf(float f) {
  __hip_bfloat16 h = __float2bfloat16(f);
  return __builtin_bit_cast(unsigned short, h);
}

// ---------------------------------------------------------------------------
// Kernel 0: cast x -> bf16; build wqk^T (64x256, q cols then k cols) and
// wv^T (256x256) in bf16.
// ---------------------------------------------------------------------------
__global__ void prep_kernel(const float* __restrict__ x,
                            const float* __restrict__ wq,
                            const float* __restrict__ wk,
                            const float* __restrict__ wv,
                            unsigned short* __restrict__ xb,
                            unsigned short* __restrict__ wqkT,
                            unsigned short* __restrict__ wvT) {
  int stride = gridDim.x * blockDim.x;
  int i0 = blockIdx.x * blockDim.x + threadIdx.x;
  const int nx4 = BATCH * NPIX * CCH / 4;
  for (int i = i0; i < nx4; i += stride) {
    float4 v = reinterpret_cast<const float4*>(x)[i];
    ushort4 o;
    o.x = f2bf(v.x); o.y = f2bf(v.y); o.z = f2bf(v.z); o.w = f2bf(v.w);
    reinterpret_cast<ushort4*>(xb)[i] = o;
  }
  for (int i = i0; i < 64 * CCH; i += stride) {
    int d = i >> 8, c = i & 255;
    float v = (d < RCH) ? wq[c * RCH + d] : wk[c * RCH + (d - RCH)];
    wqkT[i] = f2bf(v);
  }
  for (int i = i0; i < CCH * CCH; i += stride) {
    int d = i >> 8, c = i & 255;
    wvT[i] = f2bf(wv[c * CCH + d]);
  }
}

// ---------------------------------------------------------------------------
// Kernel 1: q,k projection. out[row][col] = relu(x[row,:] . w[:,col] + bias)
// rows flat over B*N (32768). 64 cols = 32 q + 32 k.
// block: 256 thr (4 waves), 64 rows; wave: 16 rows x 64 cols; K=256 (8 steps).
// ---------------------------------------------------------------------------
__global__ void qk_proj_kernel(const unsigned short* __restrict__ xb,
                               const unsigned short* __restrict__ wqkT,
                               const float* __restrict__ bq,
                               const float* __restrict__ bk,
                               unsigned short* __restrict__ qb,
                               unsigned short* __restrict__ kb) {
  int t = threadIdx.x;
  int w = t >> 6, l = t & 63, g = l >> 4, lc = l & 15;
  int row0 = blockIdx.x * 64 + w * 16;
  f32x4 zero = {0.f, 0.f, 0.f, 0.f};
  f32x4 acc[4];
  for (int ct = 0; ct < 4; ++ct) acc[ct] = zero;
  for (int ks = 0; ks < 8; ++ks) {
    s16x8 a = *reinterpret_cast<const s16x8*>(
        xb + (size_t)(row0 + lc) * CCH + ks * 32 + g * 8);
    for (int ct = 0; ct < 4; ++ct) {
      s16x8 bfr = *reinterpret_cast<const s16x8*>(
          wqkT + (size_t)(ct * 16 + lc) * CCH + ks * 32 + g * 8);
      acc[ct] = __builtin_amdgcn_mfma_f32_16x16x32_bf16(a, bfr, acc[ct], 0, 0, 0);
    }
  }
  for (int ct = 0; ct < 4; ++ct) {
    int col = ct * 16 + lc;
    float bias = (col < RCH) ? bq[col] : bk[col - RCH];
    for (int r = 0; r < 4; ++r) {
      int row = row0 + 4 * g + r;
      float v = fmaxf(acc[ct][r] + bias, 0.f);
      if (col < RCH) qb[(size_t)row * RCH + col] = f2bf(v);
      else           kb[(size_t)row * RCH + (col - RCH)] = f2bf(v);
    }
  }
}

// ---------------------------------------------------------------------------
// Kernel 2: v projection, stored TRANSPOSED: vT[b][d][n] = x[b,n,:].wv[:,d]+bv
// A = wvT (256 x 256), B^T = xb[b] (4096 x 256). Output tile 64 d x 64 n.
// grid: b(8) x dt(4) x nt(64) = 2048 blocks.
// ---------------------------------------------------------------------------
__global__ void v_proj_kernel(const unsigned short* __restrict__ xb,
                              const unsigned short* __restrict__ wvT,
                              const float* __restrict__ bv,
                              unsigned short* __restrict__ vT) {
  int t = threadIdx.x;
  int w = t >> 6, l = t & 63, g = l >> 4, lc = l & 15;
  int idx = blockIdx.x;
  int b = idx & 7; idx >>= 3;
  int dt = idx & 3; int nt = idx >> 2;
  int d0 = dt * 64 + w * 16;
  int n0 = nt * 64;
  f32x4 zero = {0.f, 0.f, 0.f, 0.f};
  f32x4 acc[4];
  for (int ct = 0; ct < 4; ++ct) acc[ct] = zero;
  for (int ks = 0; ks < 8; ++ks) {
    s16x8 a = *reinterpret_cast<const s16x8*>(
        wvT + (size_t)(d0 + lc) * CCH + ks * 32 + g * 8);
    for (int ct = 0; ct < 4; ++ct) {
      s16x8 bfr = *reinterpret_cast<const s16x8*>(
          xb + ((size_t)b * NPIX + n0 + ct * 16 + lc) * CCH + ks * 32 + g * 8);
      acc[ct] = __builtin_amdgcn_mfma_f32_16x16x32_bf16(a, bfr, acc[ct], 0, 0, 0);
    }
  }
  for (int ct = 0; ct < 4; ++ct) {
    for (int r = 0; r < 4; ++r) {
      int d = d0 + 4 * g + r;
      int n = n0 + ct * 16 + lc;
      vT[((size_t)b * CCH + d) * NPIX + n] = f2bf(acc[ct][r] + bv[d]);
    }
  }
}

// ---------------------------------------------------------------------------
// Kernel 3: flash attention + residual.
// block: 1 batch x 64 queries (4 waves x 16 q). KV tile = 64 keys.
// LDS: K (64x32 pad40), Vt (256x64 pad72), P per wave (16x64 pad72).
// ---------------------------------------------------------------------------
__global__ void attn_kernel(const unsigned short* __restrict__ qb,
                            const unsigned short* __restrict__ kb,
                            const unsigned short* __restrict__ vT,
                            const float* __restrict__ x,
                            float* __restrict__ out) {
  __shared__ __attribute__((aligned(16))) unsigned short Klds[64 * 40];
  __shared__ __attribute__((aligned(16))) unsigned short Vlds[256 * 72];
  __shared__ __attribute__((aligned(16))) unsigned short Plds[4][16 * 72];

  int b = blockIdx.x & 7;          // batch -> XCD locality for K/V reuse
  int qt = blockIdx.x >> 3;
  int t = threadIdx.x;
  int w = t >> 6, l = t & 63, g = l >> 4, lc = l & 15;
  int qbase = qt * 64 + w * 16;
  const size_t bN = (size_t)b * NPIX;

  // Q fragment: lane holds Q[qbase+lc][g*8 .. g*8+7]
  s16x8 qfrag = *reinterpret_cast<const s16x8*>(
      qb + (bN + qbase + lc) * RCH + g * 8);

  f32x4 zero = {0.f, 0.f, 0.f, 0.f};
  f32x4 o[16];
  for (int c = 0; c < 16; ++c) o[c] = zero;
  float m[4] = {-1e30f, -1e30f, -1e30f, -1e30f};
  float lsum[4] = {0.f, 0.f, 0.f, 0.f};

  for (int kv0 = 0; kv0 < NPIX; kv0 += 64) {
    // ---- stage K tile (64 rows x 32) ----
    {
      int kr = t >> 2, kc = (t & 3) * 8;
      s16x8 kv = *reinterpret_cast<const s16x8*>(
          kb + (bN + kv0 + kr) * RCH + kc);
      *reinterpret_cast<s16x8*>(&Klds[kr * 40 + kc]) = kv;
    }
    // ---- stage V tile (256 ch x 64 keys), rows contiguous from vT ----
    for (int i = 0; i < 8; ++i) {
      int ch = i * 256 + t;
      int row = ch >> 3, co = (ch & 7) * 8;
      s16x8 vv = *reinterpret_cast<const s16x8*>(
          vT + ((size_t)b * CCH + row) * NPIX + kv0 + co);
      *reinterpret_cast<s16x8*>(&Vlds[row * 72 + co]) = vv;
    }
    __syncthreads();

    // ---- QK^T: 4 key sub-tiles of 16 ----
    f32x4 s[4];
    for (int kt = 0; kt < 4; ++kt) {
      s16x8 kf = *reinterpret_cast<const s16x8*>(&Klds[(kt * 16 + lc) * 40 + g * 8]);
      s[kt] = __builtin_amdgcn_mfma_f32_16x16x32_bf16(qfrag, kf, zero, 0, 0, 0);
    }

    // ---- online softmax (query 4g+r lives in 16-lane group g, reg r) ----
    float scale[4];
    for (int r = 0; r < 4; ++r) {
      float mx = fmaxf(fmaxf(s[0][r], s[1][r]), fmaxf(s[2][r], s[3][r]));
      for (int off = 8; off >= 1; off >>= 1) mx = fmaxf(mx, __shfl_xor(mx, off));
      float mnew = fmaxf(m[r], mx);
      scale[r] = __expf(m[r] - mnew);
      float ps = 0.f;
      for (int kt = 0; kt < 4; ++kt) {
        float p = __expf(s[kt][r] - mnew);
        s[kt][r] = p;
        ps += p;
      }
      for (int off = 8; off >= 1; off >>= 1) ps += __shfl_xor(ps, off);
      lsum[r] = lsum[r] * scale[r] + ps;
      m[r] = mnew;
    }

    // ---- write P (bf16) to per-wave LDS: [query 0..15][key 0..63] ----
    for (int kt = 0; kt < 4; ++kt)
      for (int r = 0; r < 4; ++r)
        Plds[w][(4 * g + r) * 72 + kt * 16 + lc] = f2bf(s[kt][r]);

    // ---- rescale O while the LDS writes land ----
    for (int c = 0; c < 16; ++c)
      for (int r = 0; r < 4; ++r) o[c][r] *= scale[r];

    asm volatile("s_waitcnt lgkmcnt(0)" ::: "memory");

    // ---- P.V: A frags reused across 16 channel chunks ----
    s16x8 pa0 = *reinterpret_cast<const s16x8*>(&Plds[w][lc * 72 + g * 8]);
    s16x8 pa1 = *reinterpret_cast<const s16x8*>(&Plds[w][lc * 72 + 32 + g * 8]);
    for (int c = 0; c < 16; ++c) {
      s16x8 v0 = *reinterpret_cast<const s16x8*>(&Vlds[(c * 16 + lc) * 72 + g * 8]);
      s16x8 v1 = *reinterpret_cast<const s16x8*>(&Vlds[(c * 16 + lc) * 72 + 32 + g * 8]);
      o[c] = __builtin_amdgcn_mfma_f32_16x16x32_bf16(pa0, v0, o[c], 0, 0, 0);
      o[c] = __builtin_amdgcn_mfma_f32_16x16x32_bf16(pa1, v1, o[c], 0, 0, 0);
    }
    __syncthreads();
  }

  // ---- epilogue: normalize, add residual, store fp32 ----
  for (int c = 0; c < 16; ++c) {
    for (int r = 0; r < 4; ++r) {
      size_t row = bN + qbase + 4 * g + r;
      size_t idx = row * CCH + c * 16 + lc;
      out[idx] = o[c][r] / lsum[r] + x[idx];
    }
  }
}

// ---------------------------------------------------------------------------
extern "C" void kernel_launch(void* const* d_in, const int* in_sizes, int n_in,
                              void* d_out, int out_size, void* d_ws, size_t ws_size,
                              hipStream_t stream) {
  const float* x  = (const float*)d_in[0];
  const float* wq = (const float*)d_in[1];
  const float* bq = (const float*)d_in[2];
  const float* wk = (const float*)d_in[3];
  const float* bk = (const float*)d_in[4];
  const float* wv = (const float*)d_in[5];
  const float* bv = (const float*)d_in[6];
  float* out = (float*)d_out;

  unsigned short* ws   = (unsigned short*)d_ws;
  unsigned short* qb   = ws;                   // 8*4096*32  = 1,048,576
  unsigned short* kb   = qb + 1048576;         // 1,048,576
  unsigned short* vT   = kb + 1048576;         // 8*256*4096 = 8,388,608
  unsigned short* xb   = vT + 8388608;         // 8,388,608
  unsigned short* wqkT = xb + 8388608;         // 64*256 = 16,384
  unsigned short* wvT  = wqkT + 16384;         // 256*256 = 65,536

  prep_kernel<<<dim3(2048), dim3(256), 0, stream>>>(x, wq, wk, wv, xb, wqkT, wvT);
  qk_proj_kernel<<<dim3(512), dim3(256), 0, stream>>>(xb, wqkT, bq, bk, qb, kb);
  v_proj_kernel<<<dim3(2048), dim3(256), 0, stream>>>(xb, wvT, bv, vT);
  attn_kernel<<<dim3(512), dim3(256), 0, stream>>>(qb, kb, vT, x, out);
}

// Round 2
// 268.473 us; speedup vs baseline: 1.4316x; 1.4316x over previous
//
#include <hip/hip_runtime.h>
#include <hip/hip_bf16.h>

typedef __attribute__((ext_vector_type(8))) short s16x8;
typedef __attribute__((ext_vector_type(4))) float f32x4;

#define BATCH 8
#define NPIX  4096
#define CCH   256
#define RCH   32
#define KVT   64
#define NT    (NPIX / KVT)
#define THR   8.0f

__device__ __forceinline__ unsigned short f2bf(float f) {
  __hip_bfloat16 h = __float2bfloat16(f);
  return __builtin_bit_cast(unsigned short, h);
}

__device__ __forceinline__ unsigned int cvt_pk_bf16(float lo, float hi) {
  unsigned int r;
  asm volatile("v_cvt_pk_bf16_f32 %0, %1, %2" : "=v"(r) : "v"(lo), "v"(hi));
  return r;
}

// ---------------------------------------------------------------------------
// Kernel 0: cast x -> bf16; build wqk^T (64x256) and wv^T (256x256) in bf16.
// ---------------------------------------------------------------------------
__global__ void prep_kernel(const float* __restrict__ x,
                            const float* __restrict__ wq,
                            const float* __restrict__ wk,
                            const float* __restrict__ wv,
                            unsigned short* __restrict__ xb,
                            unsigned short* __restrict__ wqkT,
                            unsigned short* __restrict__ wvT) {
  int stride = gridDim.x * blockDim.x;
  int i0 = blockIdx.x * blockDim.x + threadIdx.x;
  const int nx4 = BATCH * NPIX * CCH / 4;
  for (int i = i0; i < nx4; i += stride) {
    float4 v = reinterpret_cast<const float4*>(x)[i];
    ushort4 o;
    o.x = f2bf(v.x); o.y = f2bf(v.y); o.z = f2bf(v.z); o.w = f2bf(v.w);
    reinterpret_cast<ushort4*>(xb)[i] = o;
  }
  for (int i = i0; i < 64 * CCH; i += stride) {
    int d = i >> 8, c = i & 255;
    float v = (d < RCH) ? wq[c * RCH + d] : wk[c * RCH + (d - RCH)];
    wqkT[i] = f2bf(v);
  }
  for (int i = i0; i < CCH * CCH; i += stride) {
    int d = i >> 8, c = i & 255;
    wvT[i] = f2bf(wv[c * CCH + d]);
  }
}

// ---------------------------------------------------------------------------
// Kernel 1: q,k projection with relu. rows flat over B*N; 64 cols = 32q+32k.
// ---------------------------------------------------------------------------
__global__ void qk_proj_kernel(const unsigned short* __restrict__ xb,
                               const unsigned short* __restrict__ wqkT,
                               const float* __restrict__ bq,
                               const float* __restrict__ bk,
                               unsigned short* __restrict__ qb,
                               unsigned short* __restrict__ kb) {
  int t = threadIdx.x;
  int w = t >> 6, l = t & 63, g = l >> 4, lc = l & 15;
  int row0 = blockIdx.x * 64 + w * 16;
  f32x4 zero = {0.f, 0.f, 0.f, 0.f};
  f32x4 acc[4];
  for (int ct = 0; ct < 4; ++ct) acc[ct] = zero;
  for (int ks = 0; ks < 8; ++ks) {
    s16x8 a = *reinterpret_cast<const s16x8*>(
        xb + (size_t)(row0 + lc) * CCH + ks * 32 + g * 8);
    for (int ct = 0; ct < 4; ++ct) {
      s16x8 bfr = *reinterpret_cast<const s16x8*>(
          wqkT + (size_t)(ct * 16 + lc) * CCH + ks * 32 + g * 8);
      acc[ct] = __builtin_amdgcn_mfma_f32_16x16x32_bf16(a, bfr, acc[ct], 0, 0, 0);
    }
  }
  for (int ct = 0; ct < 4; ++ct) {
    int col = ct * 16 + lc;
    float bias = (col < RCH) ? bq[col] : bk[col - RCH];
    for (int r = 0; r < 4; ++r) {
      int row = row0 + 4 * g + r;
      float v = fmaxf(acc[ct][r] + bias, 0.f);
      if (col < RCH) qb[(size_t)row * RCH + col] = f2bf(v);
      else           kb[(size_t)row * RCH + (col - RCH)] = f2bf(v);
    }
  }
}

// ---------------------------------------------------------------------------
// Kernel 2: v projection, stored transposed: vT[b][d][n]
// ---------------------------------------------------------------------------
__global__ void v_proj_kernel(const unsigned short* __restrict__ xb,
                              const unsigned short* __restrict__ wvT,
                              const float* __restrict__ bv,
                              unsigned short* __restrict__ vT) {
  int t = threadIdx.x;
  int w = t >> 6, l = t & 63, g = l >> 4, lc = l & 15;
  int idx = blockIdx.x;
  int b = idx & 7; idx >>= 3;
  int dt = idx & 3; int nt = idx >> 2;
  int d0 = dt * 64 + w * 16;
  int n0 = nt * 64;
  f32x4 zero = {0.f, 0.f, 0.f, 0.f};
  f32x4 acc[4];
  for (int ct = 0; ct < 4; ++ct) acc[ct] = zero;
  for (int ks = 0; ks < 8; ++ks) {
    s16x8 a = *reinterpret_cast<const s16x8*>(
        wvT + (size_t)(d0 + lc) * CCH + ks * 32 + g * 8);
    for (int ct = 0; ct < 4; ++ct) {
      s16x8 bfr = *reinterpret_cast<const s16x8*>(
          xb + ((size_t)b * NPIX + n0 + ct * 16 + lc) * CCH + ks * 32 + g * 8);
      acc[ct] = __builtin_amdgcn_mfma_f32_16x16x32_bf16(a, bfr, acc[ct], 0, 0, 0);
    }
  }
  for (int ct = 0; ct < 4; ++ct) {
    for (int r = 0; r < 4; ++r) {
      int d = d0 + 4 * g + r;
      int n = n0 + ct * 16 + lc;
      vT[((size_t)b * CCH + d) * NPIX + n] = f2bf(acc[ct][r] + bv[d]);
    }
  }
}

// ---------------------------------------------------------------------------
// Kernel 3: flash attention + residual.
// Block = 1 batch x 64 queries, 4 waves. S^T via mfma(K,Q): lane owns q=lc.
// PV channel-split: wave w -> ch [64w,64w+64), V frags direct from L2 (vT).
// P via XOR-swizzled LDS (stride 128B, ^=(row&7)<<4), double-buffered,
// ONE barrier per tile. Defer-max rescale (THR=8).
// ---------------------------------------------------------------------------
__global__ __launch_bounds__(256, 2)
void attn_kernel(const unsigned short* __restrict__ qb,
                 const unsigned short* __restrict__ kb,
                 const unsigned short* __restrict__ vT,
                 const float* __restrict__ x,
                 float* __restrict__ out) {
  __shared__ __attribute__((aligned(16))) unsigned short Plds[2][64 * 64];
  __shared__ __attribute__((aligned(16))) float scaleArr[2][64];
  __shared__ __attribute__((aligned(16))) int flags[2][4];
  __shared__ __attribute__((aligned(16))) float lsumArr[64];

  int b = blockIdx.x & 7;          // batch == XCD -> vT/K/Q L2-resident
  int qt = blockIdx.x >> 3;
  int t = threadIdx.x;
  int w = t >> 6, l = t & 63, g = l >> 4, lc = l & 15;
  const size_t bN = (size_t)b * NPIX;

  // this lane's query (column of S^T) for the QK phase
  int qrow = qt * 64 + w * 16 + lc;
  s16x8 qfrag = *reinterpret_cast<const s16x8*>(qb + (bN + qrow) * RCH + g * 8);

  const unsigned short* kbase = kb + bN * RCH;
  const unsigned short* vbase = vT + (size_t)b * CCH * NPIX;

  f32x4 zero = {0.f, 0.f, 0.f, 0.f};
  f32x4 o[4][4];                    // [qchunk][cchunk]; q=qc*16+4g+r, ch=64w+cc*16+lc
  for (int qc = 0; qc < 4; ++qc)
    for (int cc = 0; cc < 4; ++cc) o[qc][cc] = zero;
  float m = -1e30f, lsum = 0.f;

  for (int tix = 0; tix < NT; ++tix) {
    int kv0 = tix * KVT;
    int p = tix & 1;

    // ---- QK^T (S^T): A=K chunk from L2, B=Q regs ----
    f32x4 s[4];
    for (int ct = 0; ct < 4; ++ct) {
      s16x8 kf = *reinterpret_cast<const s16x8*>(
          kbase + (size_t)(kv0 + ct * 16 + lc) * RCH + g * 8);
      s[ct] = __builtin_amdgcn_mfma_f32_16x16x32_bf16(kf, qfrag, zero, 0, 0, 0);
    }

    // ---- online softmax for query lc (keys ct*16+4g+r in regs) ----
    float pmax = s[0][0];
    for (int ct = 0; ct < 4; ++ct)
      for (int r = 0; r < 4; ++r) pmax = fmaxf(pmax, s[ct][r]);
    pmax = fmaxf(pmax, __shfl_xor(pmax, 16));
    pmax = fmaxf(pmax, __shfl_xor(pmax, 32));

    float sc = 1.f;
    int resc = !__all(pmax - m <= THR);
    if (resc) {
      float mnew = fmaxf(m, pmax);
      sc = __expf(m - mnew);
      m = mnew;
    }

    float psum = 0.f;
    unsigned int pk[4][2];
    for (int ct = 0; ct < 4; ++ct) {
      float p0 = __expf(s[ct][0] - m);
      float p1 = __expf(s[ct][1] - m);
      float p2 = __expf(s[ct][2] - m);
      float p3 = __expf(s[ct][3] - m);
      psum += (p0 + p1) + (p2 + p3);
      pk[ct][0] = cvt_pk_bf16(p0, p1);
      pk[ct][1] = cvt_pk_bf16(p2, p3);
    }
    psum += __shfl_xor(psum, 16);
    psum += __shfl_xor(psum, 32);
    lsum = lsum * sc + psum;

    // ---- write P^T-free P[q_local][key_local] bf16, XOR-swizzled ----
    {
      int row = w * 16 + lc;
      unsigned int swz = (row & 7) << 4;
      char* base = (char*)&Plds[p][0] + row * 128;
      for (int ct = 0; ct < 4; ++ct) {
        unsigned long long v =
            ((unsigned long long)pk[ct][1] << 32) | pk[ct][0];
        *reinterpret_cast<unsigned long long*>(
            base + (((unsigned)(32 * ct + 8 * g)) ^ swz)) = v;
      }
    }
    if (l < 16) scaleArr[p][w * 16 + l] = sc;
    if (l == 0) flags[p][w] = resc;

    __syncthreads();

    // ---- rescale O only if some wave's max grew ----
    int4 fl = *reinterpret_cast<const int4*>(&flags[p][0]);
    if (fl.x | fl.y | fl.z | fl.w) {
      for (int qc = 0; qc < 4; ++qc) {
        f32x4 s4 = *reinterpret_cast<const f32x4*>(&scaleArr[p][qc * 16 + 4 * g]);
        for (int cc = 0; cc < 4; ++cc)
          for (int r = 0; r < 4; ++r) o[qc][cc][r] *= s4[r];
      }
    }

    // ---- PV: A=P (LDS, all 64 q), B=V slice direct from L2 ----
    for (int half = 0; half < 2; ++half) {
      s16x8 pa[4];
      for (int qc = 0; qc < 4; ++qc) {
        int row = qc * 16 + lc;
        unsigned int swz = (row & 7) << 4;
        pa[qc] = *reinterpret_cast<const s16x8*>(
            (char*)&Plds[p][0] + row * 128 +
            (((unsigned)(64 * half + 16 * g)) ^ swz));
      }
      s16x8 vb[4];
      for (int cc = 0; cc < 4; ++cc) {
        int ch = 64 * w + cc * 16 + lc;
        vb[cc] = *reinterpret_cast<const s16x8*>(
            vbase + (size_t)ch * NPIX + kv0 + 32 * half + 8 * g);
      }
      for (int cc = 0; cc < 4; ++cc)
        for (int qc = 0; qc < 4; ++qc)
          o[qc][cc] = __builtin_amdgcn_mfma_f32_16x16x32_bf16(
              pa[qc], vb[cc], o[qc][cc], 0, 0, 0);
    }
    // no second barrier: next tile writes the other P buffer
  }

  // ---- epilogue: share lsum, normalize, residual, store ----
  if (l < 16) lsumArr[w * 16 + l] = lsum;
  __syncthreads();
  for (int qc = 0; qc < 4; ++qc) {
    f32x4 l4 = *reinterpret_cast<const f32x4*>(&lsumArr[qc * 16 + 4 * g]);
    f32x4 rl;
    for (int r = 0; r < 4; ++r) rl[r] = 1.0f / l4[r];
    for (int cc = 0; cc < 4; ++cc) {
      for (int r = 0; r < 4; ++r) {
        size_t row = bN + qt * 64 + qc * 16 + 4 * g + r;
        size_t idx = row * CCH + 64 * w + cc * 16 + lc;
        out[idx] = o[qc][cc][r] * rl[r] + x[idx];
      }
    }
  }
}

// ---------------------------------------------------------------------------
extern "C" void kernel_launch(void* const* d_in, const int* in_sizes, int n_in,
                              void* d_out, int out_size, void* d_ws, size_t ws_size,
                              hipStream_t stream) {
  const float* x  = (const float*)d_in[0];
  const float* wq = (const float*)d_in[1];
  const float* bq = (const float*)d_in[2];
  const float* wk = (const float*)d_in[3];
  const float* bk = (const float*)d_in[4];
  const float* wv = (const float*)d_in[5];
  const float* bv = (const float*)d_in[6];
  float* out = (float*)d_out;

  unsigned short* ws   = (unsigned short*)d_ws;
  unsigned short* qb   = ws;                   // 8*4096*32  = 1,048,576
  unsigned short* kb   = qb + 1048576;         // 1,048,576
  unsigned short* vT   = kb + 1048576;         // 8*256*4096 = 8,388,608
  unsigned short* xb   = vT + 8388608;         // 8,388,608
  unsigned short* wqkT = xb + 8388608;         // 64*256 = 16,384
  unsigned short* wvT  = wqkT + 16384;         // 256*256 = 65,536

  prep_kernel<<<dim3(2048), dim3(256), 0, stream>>>(x, wq, wk, wv, xb, wqkT, wvT);
  qk_proj_kernel<<<dim3(512), dim3(256), 0, stream>>>(xb, wqkT, bq, bk, qb, kb);
  v_proj_kernel<<<dim3(2048), dim3(256), 0, stream>>>(xb, wvT, bv, vT);
  attn_kernel<<<dim3(512), dim3(256), 0, stream>>>(qb, kb, vT, x, out);
}

// Round 4
// 213.125 us; speedup vs baseline: 1.8034x; 1.2597x over previous
//
#include <hip/hip_runtime.h>
#include <hip/hip_bf16.h>

typedef __attribute__((ext_vector_type(8))) short s16x8;
typedef __attribute__((ext_vector_type(4))) float f32x4;

#define BATCH 8
#define NPIX  4096
#define CCH   256
#define RCH   32
#define KVT   64
#define NT    (NPIX / KVT)
#define THR   8.0f

__device__ __forceinline__ unsigned short f2bf(float f) {
  __hip_bfloat16 h = __float2bfloat16(f);
  return __builtin_bit_cast(unsigned short, h);
}

__device__ __forceinline__ unsigned int pack_bf16(float lo, float hi) {
  return (unsigned int)f2bf(lo) | ((unsigned int)f2bf(hi) << 16);
}

// ---------------------------------------------------------------------------
// Kernel 0: cast x -> bf16; build wqk^T (64x256) and wv^T (256x256) in bf16.
// ---------------------------------------------------------------------------
__global__ void prep_kernel(const float* __restrict__ x,
                            const float* __restrict__ wq,
                            const float* __restrict__ wk,
                            const float* __restrict__ wv,
                            unsigned short* __restrict__ xb,
                            unsigned short* __restrict__ wqkT,
                            unsigned short* __restrict__ wvT) {
  int stride = gridDim.x * blockDim.x;
  int i0 = blockIdx.x * blockDim.x + threadIdx.x;
  const int nx4 = BATCH * NPIX * CCH / 4;
  for (int i = i0; i < nx4; i += stride) {
    float4 v = reinterpret_cast<const float4*>(x)[i];
    ushort4 o;
    o.x = f2bf(v.x); o.y = f2bf(v.y); o.z = f2bf(v.z); o.w = f2bf(v.w);
    reinterpret_cast<ushort4*>(xb)[i] = o;
  }
  for (int i = i0; i < 64 * CCH; i += stride) {
    int d = i >> 8, c = i & 255;
    float v = (d < RCH) ? wq[c * RCH + d] : wk[c * RCH + (d - RCH)];
    wqkT[i] = f2bf(v);
  }
  for (int i = i0; i < CCH * CCH; i += stride) {
    int d = i >> 8, c = i & 255;
    wvT[i] = f2bf(wv[c * CCH + d]);
  }
}

// ---------------------------------------------------------------------------
// Kernel 1: q,k projection with relu. rows flat over B*N; 64 cols = 32q+32k.
// ---------------------------------------------------------------------------
__global__ void qk_proj_kernel(const unsigned short* __restrict__ xb,
                               const unsigned short* __restrict__ wqkT,
                               const float* __restrict__ bq,
                               const float* __restrict__ bk,
                               unsigned short* __restrict__ qb,
                               unsigned short* __restrict__ kb) {
  int t = threadIdx.x;
  int w = t >> 6, l = t & 63, g = l >> 4, lc = l & 15;
  int row0 = blockIdx.x * 64 + w * 16;
  f32x4 zero = {0.f, 0.f, 0.f, 0.f};
  f32x4 acc[4];
  for (int ct = 0; ct < 4; ++ct) acc[ct] = zero;
  for (int ks = 0; ks < 8; ++ks) {
    s16x8 a = *reinterpret_cast<const s16x8*>(
        xb + (size_t)(row0 + lc) * CCH + ks * 32 + g * 8);
    for (int ct = 0; ct < 4; ++ct) {
      s16x8 bfr = *reinterpret_cast<const s16x8*>(
          wqkT + (size_t)(ct * 16 + lc) * CCH + ks * 32 + g * 8);
      acc[ct] = __builtin_amdgcn_mfma_f32_16x16x32_bf16(a, bfr, acc[ct], 0, 0, 0);
    }
  }
  for (int ct = 0; ct < 4; ++ct) {
    int col = ct * 16 + lc;
    float bias = (col < RCH) ? bq[col] : bk[col - RCH];
    for (int r = 0; r < 4; ++r) {
      int row = row0 + 4 * g + r;
      float v = fmaxf(acc[ct][r] + bias, 0.f);
      if (col < RCH) qb[(size_t)row * RCH + col] = f2bf(v);
      else           kb[(size_t)row * RCH + (col - RCH)] = f2bf(v);
    }
  }
}

// ---------------------------------------------------------------------------
// Kernel 2: v projection, stored transposed: vT[b][d][n]
// ---------------------------------------------------------------------------
__global__ void v_proj_kernel(const unsigned short* __restrict__ xb,
                              const unsigned short* __restrict__ wvT,
                              const float* __restrict__ bv,
                              unsigned short* __restrict__ vT) {
  int t = threadIdx.x;
  int w = t >> 6, l = t & 63, g = l >> 4, lc = l & 15;
  int idx = blockIdx.x;
  int b = idx & 7; idx >>= 3;
  int dt = idx & 3; int nt = idx >> 2;
  int d0 = dt * 64 + w * 16;
  int n0 = nt * 64;
  f32x4 zero = {0.f, 0.f, 0.f, 0.f};
  f32x4 acc[4];
  for (int ct = 0; ct < 4; ++ct) acc[ct] = zero;
  for (int ks = 0; ks < 8; ++ks) {
    s16x8 a = *reinterpret_cast<const s16x8*>(
        wvT + (size_t)(d0 + lc) * CCH + ks * 32 + g * 8);
    for (int ct = 0; ct < 4; ++ct) {
      s16x8 bfr = *reinterpret_cast<const s16x8*>(
          xb + ((size_t)b * NPIX + n0 + ct * 16 + lc) * CCH + ks * 32 + g * 8);
      acc[ct] = __builtin_amdgcn_mfma_f32_16x16x32_bf16(a, bfr, acc[ct], 0, 0, 0);
    }
  }
  for (int ct = 0; ct < 4; ++ct) {
    for (int r = 0; r < 4; ++r) {
      int d = d0 + 4 * g + r;
      int n = n0 + ct * 16 + lc;
      vT[((size_t)b * CCH + d) * NPIX + n] = f2bf(acc[ct][r] + bv[d]);
    }
  }
}

// ---------------------------------------------------------------------------
// Kernel 3: flash attention + residual. Producer/consumer wave split.
// Block = 1 batch x 64 queries, 8 waves (512 thr).
//   waves 0-3 (producer): QK^T (S^T via mfma(K,Q)), softmax, P -> LDS.
//   waves 4-7 (consumer): rescale O, P.V for their 64-channel slice.
// P double-buffered + XOR swizzle; ONE barrier per tile; defer-max (THR=8).
// K prefetched one tile ahead in regs; V loads issued pre-barrier.
// ---------------------------------------------------------------------------
__global__ __launch_bounds__(512, 4)
void attn_kernel(const unsigned short* __restrict__ qb,
                 const unsigned short* __restrict__ kb,
                 const unsigned short* __restrict__ vT,
                 const float* __restrict__ x,
                 float* __restrict__ out) {
  __shared__ __attribute__((aligned(16))) unsigned short Plds[2][64 * 64];
  __shared__ __attribute__((aligned(16))) float scaleArr[2][64];
  __shared__ __attribute__((aligned(16))) int flags[2][4];
  __shared__ __attribute__((aligned(16))) float lsumArr[64];

  int b = blockIdx.x & 7;          // batch == XCD -> vT/K/Q L2-resident
  int qt = blockIdx.x >> 3;
  int t = threadIdx.x;
  int w = t >> 6, l = t & 63, g = l >> 4, lc = l & 15;
  const size_t bN = (size_t)b * NPIX;
  f32x4 zero = {0.f, 0.f, 0.f, 0.f};

  if (w < 4) {
    // ================= producer =================
    int qrow = qt * 64 + w * 16 + lc;
    s16x8 qfrag = *reinterpret_cast<const s16x8*>(qb + (bN + qrow) * RCH + g * 8);
    const unsigned short* kbase = kb + bN * RCH;
    float m = -1e30f, lsum = 0.f;

    s16x8 kf[4];
    for (int ct = 0; ct < 4; ++ct)
      kf[ct] = *reinterpret_cast<const s16x8*>(
          kbase + (size_t)(ct * 16 + lc) * RCH + g * 8);

    for (int tix = 0; tix < NT; ++tix) {
      int p = tix & 1;

      f32x4 s[4];
      for (int ct = 0; ct < 4; ++ct)
        s[ct] = __builtin_amdgcn_mfma_f32_16x16x32_bf16(kf[ct], qfrag, zero, 0, 0, 0);

      // prefetch next K tile (wraps harmlessly on last iter)
      int tn = (tix + 1) & (NT - 1);
      for (int ct = 0; ct < 4; ++ct)
        kf[ct] = *reinterpret_cast<const s16x8*>(
            kbase + (size_t)(tn * KVT + ct * 16 + lc) * RCH + g * 8);

      // online softmax for query lc
      float pmax = s[0][0];
      for (int ct = 0; ct < 4; ++ct)
        for (int r = 0; r < 4; ++r) pmax = fmaxf(pmax, s[ct][r]);
      pmax = fmaxf(pmax, __shfl_xor(pmax, 16));
      pmax = fmaxf(pmax, __shfl_xor(pmax, 32));

      float sc = 1.f;
      int resc = !__all(pmax - m <= THR);
      if (resc) {
        float mnew = fmaxf(m, pmax);
        sc = __expf(m - mnew);
        m = mnew;
      }

      float psum = 0.f;
      unsigned int pk[4][2];
      for (int ct = 0; ct < 4; ++ct) {
        float p0 = __expf(s[ct][0] - m);
        float p1 = __expf(s[ct][1] - m);
        float p2 = __expf(s[ct][2] - m);
        float p3 = __expf(s[ct][3] - m);
        psum += (p0 + p1) + (p2 + p3);
        pk[ct][0] = pack_bf16(p0, p1);
        pk[ct][1] = pack_bf16(p2, p3);
      }
      psum += __shfl_xor(psum, 16);
      psum += __shfl_xor(psum, 32);
      lsum = lsum * sc + psum;

      // write P[q_local][key_local] bf16, XOR-swizzled rows of 128B
      {
        int row = w * 16 + lc;
        unsigned int swz = (row & 7) << 4;
        char* base = (char*)&Plds[p][0] + row * 128;
        for (int ct = 0; ct < 4; ++ct) {
          unsigned long long v =
              ((unsigned long long)pk[ct][1] << 32) | pk[ct][0];
          *reinterpret_cast<unsigned long long*>(
              base + (((unsigned)(32 * ct + 8 * g)) ^ swz)) = v;
        }
      }
      if (l < 16) scaleArr[p][w * 16 + l] = sc;
      if (l == 0) flags[p][w] = resc;

      __syncthreads();
    }

    if (l < 16) lsumArr[w * 16 + l] = lsum;
    __syncthreads();
  } else {
    // ================= consumer =================
    int wc = w - 4;                      // channel quarter [64wc, 64wc+64)
    const unsigned short* vbase = vT + (size_t)b * CCH * NPIX;
    int voff[4];
    for (int cc = 0; cc < 4; ++cc)
      voff[cc] = (64 * wc + cc * 16 + lc) * NPIX;

    f32x4 o[4][4];
    for (int qc = 0; qc < 4; ++qc)
      for (int cc = 0; cc < 4; ++cc) o[qc][cc] = zero;

    for (int tix = 0; tix < NT; ++tix) {
      int p = tix & 1;
      int kv0 = tix * KVT;

      // V half-0 loads issued before the barrier (read-only global, no race)
      s16x8 vb0[4];
      for (int cc = 0; cc < 4; ++cc)
        vb0[cc] = *reinterpret_cast<const s16x8*>(
            vbase + (size_t)voff[cc] + kv0 + 8 * g);

      __syncthreads();

      int4 fl = *reinterpret_cast<const int4*>(&flags[p][0]);
      if (fl.x | fl.y | fl.z | fl.w) {
        for (int qc = 0; qc < 4; ++qc) {
          f32x4 s4 = *reinterpret_cast<const f32x4*>(&scaleArr[p][qc * 16 + 4 * g]);
          for (int cc = 0; cc < 4; ++cc)
            for (int r = 0; r < 4; ++r) o[qc][cc][r] *= s4[r];
        }
      }

      s16x8 pa[4];
      for (int qc = 0; qc < 4; ++qc) {
        int row = qc * 16 + lc;
        unsigned int swz = (row & 7) << 4;
        pa[qc] = *reinterpret_cast<const s16x8*>(
            (char*)&Plds[p][0] + row * 128 + (((unsigned)(16 * g)) ^ swz));
      }
      // V half-1 loads issued before half-0 MFMAs
      s16x8 vb1[4];
      for (int cc = 0; cc < 4; ++cc)
        vb1[cc] = *reinterpret_cast<const s16x8*>(
            vbase + (size_t)voff[cc] + kv0 + 32 + 8 * g);

      for (int cc = 0; cc < 4; ++cc)
        for (int qc = 0; qc < 4; ++qc)
          o[qc][cc] = __builtin_amdgcn_mfma_f32_16x16x32_bf16(
              pa[qc], vb0[cc], o[qc][cc], 0, 0, 0);

      for (int qc = 0; qc < 4; ++qc) {
        int row = qc * 16 + lc;
        unsigned int swz = (row & 7) << 4;
        pa[qc] = *reinterpret_cast<const s16x8*>(
            (char*)&Plds[p][0] + row * 128 + (((unsigned)(64 + 16 * g)) ^ swz));
      }
      for (int cc = 0; cc < 4; ++cc)
        for (int qc = 0; qc < 4; ++qc)
          o[qc][cc] = __builtin_amdgcn_mfma_f32_16x16x32_bf16(
              pa[qc], vb1[cc], o[qc][cc], 0, 0, 0);
    }

    __syncthreads();   // lsumArr ready

    for (int qc = 0; qc < 4; ++qc) {
      f32x4 l4 = *reinterpret_cast<const f32x4*>(&lsumArr[qc * 16 + 4 * g]);
      f32x4 rl;
      for (int r = 0; r < 4; ++r) rl[r] = 1.0f / l4[r];
      for (int cc = 0; cc < 4; ++cc) {
        for (int r = 0; r < 4; ++r) {
          size_t row = bN + qt * 64 + qc * 16 + 4 * g + r;
          size_t idx = row * CCH + 64 * wc + cc * 16 + lc;
          out[idx] = o[qc][cc][r] * rl[r] + x[idx];
        }
      }
    }
  }
}

// ---------------------------------------------------------------------------
extern "C" void kernel_launch(void* const* d_in, const int* in_sizes, int n_in,
                              void* d_out, int out_size, void* d_ws, size_t ws_size,
                              hipStream_t stream) {
  const float* x  = (const float*)d_in[0];
  const float* wq = (const float*)d_in[1];
  const float* bq = (const float*)d_in[2];
  const float* wk = (const float*)d_in[3];
  const float* bk = (const float*)d_in[4];
  const float* wv = (const float*)d_in[5];
  const float* bv = (const float*)d_in[6];
  float* out = (float*)d_out;

  unsigned short* ws   = (unsigned short*)d_ws;
  unsigned short* qb   = ws;                   // 8*4096*32  = 1,048,576
  unsigned short* kb   = qb + 1048576;         // 1,048,576
  unsigned short* vT   = kb + 1048576;         // 8*256*4096 = 8,388,608
  unsigned short* xb   = vT + 8388608;         // 8,388,608
  unsigned short* wqkT = xb + 8388608;         // 64*256 = 16,384
  unsigned short* wvT  = wqkT + 16384;         // 256*256 = 65,536

  prep_kernel<<<dim3(2048), dim3(256), 0, stream>>>(x, wq, wk, wv, xb, wqkT, wvT);
  qk_proj_kernel<<<dim3(512), dim3(256), 0, stream>>>(xb, wqkT, bq, bk, qb, kb);
  v_proj_kernel<<<dim3(2048), dim3(256), 0, stream>>>(xb, wvT, bv, vT);
  attn_kernel<<<dim3(512), dim3(512), 0, stream>>>(qb, kb, vT, x, out);
}